// Round 1
// baseline (11810.703 us; speedup 1.0000x reference)
//
#include <hip/hip_runtime.h>
#include <cmath>

constexpr int cB = 512, cT = 64, cD = 512, cH = 8, cDH = 64, cFF = 2048;
constexpr float cSCALE = 0.125f;  // DH^-0.5

enum GemmMode { MQ = 0, MMETA1, MMETA2, MKVAE, MWO, MFF1, MFF2 };

struct GemmArgs {
  const float *A, *A2, *sm, *sr, *g, *b;
  const float *W, *Wb, *Wc, *Wd;
  const float *bias, *bias2, *extra;
  float *O, *O2, *O3, *O4;
};

// ---------------- A-loaders (row r, k) ----------------
template<int MODE>
__device__ __forceinline__ float loadA(const GemmArgs& p, int r, int k) {
  if constexpr (MODE == MQ) {
    // rows: r = t*B + b, t<64 -> item_seq[b][t], t==64 -> last_item[b]
    int t = r >> 9, bb = r & 511;
    float v = (t < cT) ? p.A[((size_t)bb * cT + t) * cD + k]
                       : p.A2[(size_t)bb * cD + k];
    return (v - p.sm[r]) * p.sr[r] * p.g[k] + p.b[k];
  } else if constexpr (MODE == MMETA1) {
    return (k < cD) ? p.A[(size_t)r * cD + k] : p.A2[(size_t)r * cD + (k - cD)];
  } else if constexpr (MODE == MMETA2) {
    float v = (p.A[(size_t)r * cD + k] - p.sm[r]) * p.sr[r] * p.g[k] + p.b[k];
    return fmaxf(v, 0.f);  // relu(LN(r_buf))
  } else if constexpr (MODE == MFF1) {
    return (p.A[(size_t)r * cD + k] - p.sm[r]) * p.sr[r] * p.g[k] + p.b[k];
  } else if constexpr (MODE == MFF2) {
    return p.A[(size_t)r * cFF + k];
  } else {  // MKVAE, MWO
    return p.A[(size_t)r * cD + k];
  }
}

// ---------------- W-loaders (k, n) ----------------
template<int MODE>
__device__ __forceinline__ float loadW(const GemmArgs& p, int k, int n) {
  if constexpr (MODE == MMETA2) {
    return p.W[(size_t)k * 1040 + n];
  } else if constexpr (MODE == MKVAE) {
    if (n < 512)       return p.W [(size_t)k * cD + n];          // Wk
    else if (n < 1024) return p.Wb[(size_t)k * cD + (n - 512)];  // Wv
    else if (n < 1032) return p.Wc[(size_t)k * cH + (n - 1024)]; // Wa
    else               return p.Wd[(size_t)k * cH + (n - 1032)]; // We
  } else if constexpr (MODE == MFF1) {
    return p.W[(size_t)k * cFF + n];
  } else {  // MQ, MMETA1, MWO, MFF2 : ldw = 512
    return p.W[(size_t)k * cD + n];
  }
}

__device__ __forceinline__ float sigm(float z) { return 1.f / (1.f + __expf(-z)); }

// ---------------- epilogues ----------------
template<int MODE>
__device__ __forceinline__ void epi(const GemmArgs& p, int r, int cn, float acc) {
  if constexpr (MODE == MQ) {
    p.O[(size_t)r * cD + cn] = acc;  // raw q (l2n applied at consumer)
  } else if constexpr (MODE == MMETA1) {
    p.O[(size_t)r * cD + cn] = acc + p.bias[cn];
  } else if constexpr (MODE == MMETA2) {
    p.O[(size_t)r * 1040 + cn] = acc + p.bias[cn];
  } else if constexpr (MODE == MKVAE) {
    if (cn < 512) {
      p.O[(size_t)r * cD + cn] = acc;                       // k raw
    } else if (cn < 1024) {
      p.O2[(size_t)r * cD + (cn - 512)] = acc;              // v
    } else if (cn < 1032) {
      int h = cn - 1024;
      p.O3[r * cH + h] = sigm(acc + p.bias[h] + p.extra[r * 16 + h]);          // alpha
    } else {
      int h = cn - 1032;
      p.O4[r * cH + h] = cSCALE * sigm(acc + p.bias2[h] + p.extra[r * 16 + 8 + h]); // eta
    }
  } else if constexpr (MODE == MWO) {
    p.O[(size_t)r * cD + cn] = p.extra[(size_t)r * cD + cn] + acc + p.bias[cn]; // x = user + attn
  } else if constexpr (MODE == MFF1) {
    float v = acc + p.bias[cn];
    p.O[(size_t)r * cFF + cn] = fmaxf(v, 0.f);
  } else {  // MFF2: out = x + ffn
    p.O[(size_t)r * cD + cn] = p.extra[(size_t)r * cD + cn] + acc + p.bias[cn];
  }
}

// ---------------- generic fp32 tiled GEMM ----------------
// 256 threads; tile TM x TN; thread computes RM x CN; K-panel 32.
template<int MODE, int TM, int TN, int RM, int CN, int K, int NV>
__global__ __launch_bounds__(256) void gemm_k(GemmArgs p) {
  __shared__ float As[32][TM + 4];
  __shared__ float Ws[32][TN];
  const int tid = threadIdx.x;
  const int tx = tid & 15, ty = tid >> 4;
  const int row0 = blockIdx.x * TM;
  const int n0 = blockIdx.y * TN;

  float acc[RM][CN];
#pragma unroll
  for (int i = 0; i < RM; ++i)
#pragma unroll
    for (int j = 0; j < CN; ++j) acc[i][j] = 0.f;

  for (int k0 = 0; k0 < K; k0 += 32) {
#pragma unroll
    for (int it = 0; it < (TM * 32) / 256; ++it) {
      int idx = it * 256 + tid;
      int kk = idx & 31, m = idx >> 5;
      As[kk][m] = loadA<MODE>(p, row0 + m, k0 + kk);
    }
#pragma unroll
    for (int it = 0; it < (TN * 32) / 256; ++it) {
      int idx = it * 256 + tid;
      int n = idx % TN, kk = idx / TN;
      float w = 0.f;
      if (NV == 0 || n0 + n < NV) w = loadW<MODE>(p, k0 + kk, n0 + n);
      Ws[kk][n] = w;
    }
    __syncthreads();
#pragma unroll
    for (int kk = 0; kk < 32; ++kk) {
      float a[RM], w[CN];
#pragma unroll
      for (int i = 0; i < RM; ++i) a[i] = As[kk][ty * RM + i];
#pragma unroll
      for (int j = 0; j < CN; ++j) w[j] = Ws[kk][tx * CN + j];
#pragma unroll
      for (int i = 0; i < RM; ++i)
#pragma unroll
        for (int j = 0; j < CN; ++j) acc[i][j] += a[i] * w[j];
    }
    __syncthreads();
  }

#pragma unroll
  for (int i = 0; i < RM; ++i) {
    int r = row0 + ty * RM + i;
#pragma unroll
    for (int j = 0; j < CN; ++j) {
      int cn = n0 + tx * CN + j;
      if (NV == 0 || cn < NV) epi<MODE>(p, r, cn, acc[i][j]);
    }
  }
}

// ---------------- LN stats for item/last rows + us_norm ----------------
// waves: [0, T*B) items (r = t*B+b); [T*B, T*B+B) last; [T*B+B, T*B+2B) user
__global__ __launch_bounds__(256) void ln_stats_k(
    const float* __restrict__ item_seq, const float* __restrict__ last_item,
    const float* __restrict__ user, const float* __restrict__ n1g,
    const float* __restrict__ n1b, float* __restrict__ lnm,
    float* __restrict__ lnr, float* __restrict__ us_norm) {
  const int lane = threadIdx.x & 63;
  const int w = blockIdx.x * 4 + (threadIdx.x >> 6);
  const float* src;
  int cls, bi = 0;
  if (w < cT * cB) {
    int t = w >> 9, bb = w & 511;
    src = item_seq + ((size_t)bb * cT + t) * cD;
    cls = 0;
  } else if (w < cT * cB + cB) {
    bi = w - cT * cB;
    src = last_item + (size_t)bi * cD;
    cls = 1;
  } else {
    bi = w - cT * cB - cB;
    src = user + (size_t)bi * cD;
    cls = 2;
  }
  float x[8], s = 0.f, ss = 0.f;
#pragma unroll
  for (int i = 0; i < 8; ++i) {
    float v = src[lane + i * 64];
    x[i] = v; s += v; ss += v * v;
  }
#pragma unroll
  for (int o = 32; o >= 1; o >>= 1) { s += __shfl_xor(s, o); ss += __shfl_xor(ss, o); }
  float m = s * (1.f / cD);
  float rstd = rsqrtf(ss * (1.f / cD) - m * m + 1e-5f);
  if (cls == 0) {
    if (lane == 0) { lnm[w] = m; lnr[w] = rstd; }
  } else if (cls == 1) {
    if (lane == 0) { lnm[cT * cB + bi] = m; lnr[cT * cB + bi] = rstd; }
  } else {
#pragma unroll
    for (int i = 0; i < 8; ++i) {
      int d = lane + i * 64;
      us_norm[(size_t)bi * cD + d] = (x[i] - m) * rstd * n1g[d] + n1b[d];
    }
  }
}

// ---------------- generic per-row stats (512 rows x 512 cols) ----------------
__global__ __launch_bounds__(256) void row_stats_k(const float* __restrict__ X,
                                                   float* __restrict__ M,
                                                   float* __restrict__ R) {
  const int lane = threadIdx.x & 63;
  const int w = blockIdx.x * 4 + (threadIdx.x >> 6);
  float s = 0.f, ss = 0.f;
#pragma unroll
  for (int i = 0; i < 8; ++i) {
    float v = X[(size_t)w * cD + lane + i * 64];
    s += v; ss += v * v;
  }
#pragma unroll
  for (int o = 32; o >= 1; o >>= 1) { s += __shfl_xor(s, o); ss += __shfl_xor(ss, o); }
  if (lane == 0) {
    float m = s * (1.f / cD);
    M[w] = m;
    R[w] = rsqrtf(ss * (1.f / cD) - m * m + 1e-5f);
  }
}

// ---------------- mod = i_norm*(1+tanh(gamma)) + beta ; extract alpha/eta bias ----------------
__global__ __launch_bounds__(256) void mod_k(
    const float* __restrict__ mo, const float* __restrict__ item_seq,
    const float* __restrict__ lnm, const float* __restrict__ lnr,
    const float* __restrict__ n1g, const float* __restrict__ n1b,
    float* __restrict__ mod, float* __restrict__ abias, int t) {
  int idx = blockIdx.x * 256 + threadIdx.x;  // over 512*528
  int b = idx / 528;
  int c = idx - b * 528;
  if (c < 512) {
    float gam = mo[(size_t)b * 1040 + c];
    float bet = mo[(size_t)b * 1040 + 512 + c];
    float inm = (item_seq[((size_t)b * cT + t) * cD + c] - lnm[t * cB + b]) *
                    lnr[t * cB + b] * n1g[c] + n1b[c];
    mod[(size_t)b * cD + c] = inm * (1.f + tanhf(gam)) + bet;
  } else {
    abias[b * 16 + (c - 512)] = mo[(size_t)b * 1040 + 1024 + (c - 512)];
  }
}

// ---------------- fused state update + memory read ----------------
// one wave per (b,h); lane i holds state row i (64 floats in VGPRs)
template<bool UPD>
__global__ __launch_bounds__(256) void state_k(
    const float* __restrict__ Sin, float* __restrict__ Sout,
    const float* __restrict__ k_raw, const float* __restrict__ v_buf,
    const float* __restrict__ alpha, const float* __restrict__ eta,
    const float* __restrict__ q_row, float* __restrict__ mem_ctx) {
  const int lane = threadIdx.x & 63;
  const int wi = threadIdx.x >> 6;
  const int w = blockIdx.x * 4 + wi;
  const int b = w >> 3, h = w & 7;
  __shared__ float sk[4][64];
  __shared__ float sq[4][64];

  float q = q_row[(size_t)b * cD + h * cDH + lane];
  float qs = q * q;
#pragma unroll
  for (int o = 32; o >= 1; o >>= 1) qs += __shfl_xor(qs, o);
  sq[wi][lane] = q / fmaxf(sqrtf(qs), 1e-12f);

  if constexpr (UPD) {
    float kv = k_raw[(size_t)b * cD + h * cDH + lane];
    float ks = kv * kv;
#pragma unroll
    for (int o = 32; o >= 1; o >>= 1) ks += __shfl_xor(ks, o);
    sk[wi][lane] = kv / fmaxf(sqrtf(ks), 1e-12f);
  }
  // only intra-wave LDS use: no __syncthreads needed

  float S[64];
  const float* sp = Sin + ((size_t)w * cDH + lane) * cDH;
#pragma unroll
  for (int j = 0; j < 64; j += 4) {
    float4 t4 = *(const float4*)(sp + j);
    S[j] = t4.x; S[j + 1] = t4.y; S[j + 2] = t4.z; S[j + 3] = t4.w;
  }

  float mem = 0.f;
  if constexpr (UPD) {
    float vv = v_buf[(size_t)b * cD + h * cDH + lane];
    float a = alpha[b * cH + h];
    float e = eta[b * cH + h];
    float pred = 0.f;
#pragma unroll
    for (int j = 0; j < 64; ++j) pred += S[j] * sk[wi][j];
    float f = e * (vv - pred);
    float oma = 1.f - a;
#pragma unroll
    for (int j = 0; j < 64; ++j) {
      S[j] = oma * S[j] + f * sk[wi][j];
      mem += S[j] * sq[wi][j];
    }
    float* op = Sout + ((size_t)w * cDH + lane) * cDH;
#pragma unroll
    for (int j = 0; j < 64; j += 4) {
      float4 t4 = make_float4(S[j], S[j + 1], S[j + 2], S[j + 3]);
      *(float4*)(op + j) = t4;
    }
  } else {
#pragma unroll
    for (int j = 0; j < 64; ++j) mem += S[j] * sq[wi][j];
  }
  mem_ctx[(size_t)b * cD + h * cDH + lane] = mem;
}

// ---------------- host launch ----------------
extern "C" void kernel_launch(void* const* d_in, const int* in_sizes, int n_in,
                              void* d_out, int out_size, void* d_ws, size_t ws_size,
                              hipStream_t stream) {
  (void)in_sizes; (void)n_in; (void)out_size;
  const float* item_seq   = (const float*)d_in[0];
  const float* user_stat  = (const float*)d_in[1];
  const float* last_item  = (const float*)d_in[2];
  const float* init_state = (const float*)d_in[3];
  const float* Wq  = (const float*)d_in[4];
  const float* Wk  = (const float*)d_in[5];
  const float* Wv  = (const float*)d_in[6];
  const float* Wa  = (const float*)d_in[7];
  const float* ba  = (const float*)d_in[8];
  const float* We  = (const float*)d_in[9];
  const float* be  = (const float*)d_in[10];
  const float* mcW1 = (const float*)d_in[11];
  const float* mcb1 = (const float*)d_in[12];
  const float* mcg  = (const float*)d_in[13];
  const float* mcbt = (const float*)d_in[14];
  const float* mcW2 = (const float*)d_in[15];
  const float* mcb2 = (const float*)d_in[16];
  const float* Wo  = (const float*)d_in[17];
  const float* bo  = (const float*)d_in[18];
  const float* W1  = (const float*)d_in[19];
  const float* b1  = (const float*)d_in[20];
  const float* W2  = (const float*)d_in[21];
  const float* b2  = (const float*)d_in[22];
  const float* n1g = (const float*)d_in[23];
  const float* n1b = (const float*)d_in[24];
  const float* n2g = (const float*)d_in[25];
  const float* n2b = (const float*)d_in[26];

  float* ws = (float*)d_ws;
  size_t off = 0;
  auto alloc = [&](size_t n) { float* p = ws + off; off += n; return p; };
  float* q_all   = alloc((size_t)(cT + 1) * cB * cD);  // 65*512*512
  float* state   = alloc((size_t)cB * cH * cDH * cDH);
  float* lnm     = alloc((size_t)(cT + 1) * cB);
  float* lnr     = alloc((size_t)(cT + 1) * cB);
  float* us_norm = alloc((size_t)cB * cD);
  float* mem_ctx = alloc((size_t)cB * cD);
  float* r_buf   = alloc((size_t)cB * cD);
  float* rm      = alloc(cB);
  float* rr      = alloc(cB);
  float* mo_buf  = alloc((size_t)cB * 1040);
  float* mod_buf = alloc((size_t)cB * cD);
  float* abias   = alloc((size_t)cB * 16);
  float* k_raw   = alloc((size_t)cB * cD);
  float* v_buf   = alloc((size_t)cB * cD);
  float* alpha_b = alloc((size_t)cB * cH);
  float* eta_b   = alloc((size_t)cB * cH);
  float* x_buf   = alloc((size_t)cB * cD);
  float* xm      = alloc(cB);
  float* xr      = alloc(cB);
  float* u_buf   = alloc((size_t)cB * cFF);
  if (ws_size < off * sizeof(float)) return;  // insufficient workspace

  // U1: LN stats for all item rows + last rows, plus us_norm
  ln_stats_k<<<(cT * cB + 2 * cB) / 4, 256, 0, stream>>>(
      item_seq, last_item, user_stat, n1g, n1b, lnm, lnr, us_norm);

  // U2: q_all = i_norm @ Wq for all 65 slots (raw, l2n at consumer)
  {
    GemmArgs p{}; p.A = item_seq; p.A2 = last_item; p.sm = lnm; p.sr = lnr;
    p.g = n1g; p.b = n1b; p.W = Wq; p.O = q_all;
    dim3 grid((cT + 1) * cB / 64, cD / 64);
    gemm_k<MQ, 64, 64, 4, 4, 512, 0><<<grid, 256, 0, stream>>>(p);
  }

  // U3: mem_ctx_0 = init_state . q_0
  state_k<false><<<cB * cH / 4, 256, 0, stream>>>(
      init_state, nullptr, nullptr, nullptr, nullptr, nullptr, q_all, mem_ctx);

  for (int t = 0; t < cT; ++t) {
    {  // G1: r = [us_norm|mem_ctx] @ mcW1 + mcb1
      GemmArgs p{}; p.A = us_norm; p.A2 = mem_ctx; p.W = mcW1; p.bias = mcb1; p.O = r_buf;
      gemm_k<MMETA1, 32, 32, 2, 2, 1024, 0><<<dim3(16, 16), 256, 0, stream>>>(p);
    }
    row_stats_k<<<cB / 4, 256, 0, stream>>>(r_buf, rm, rr);
    {  // G2: mo = relu(LN(r)) @ mcW2 + mcb2
      GemmArgs p{}; p.A = r_buf; p.sm = rm; p.sr = rr; p.g = mcg; p.b = mcbt;
      p.W = mcW2; p.bias = mcb2; p.O = mo_buf;
      gemm_k<MMETA2, 32, 32, 2, 2, 512, 1040><<<dim3(16, 33), 256, 0, stream>>>(p);
    }
    mod_k<<<cB * 528 / 256, 256, 0, stream>>>(mo_buf, item_seq, lnm, lnr, n1g, n1b,
                                              mod_buf, abias, t);
    {  // G3: [k|v|alpha|eta] = mod @ [Wk|Wv|Wa|We] (+bias, sigmoid)
      GemmArgs p{}; p.A = mod_buf; p.W = Wk; p.Wb = Wv; p.Wc = Wa; p.Wd = We;
      p.bias = ba; p.bias2 = be; p.extra = abias;
      p.O = k_raw; p.O2 = v_buf; p.O3 = alpha_b; p.O4 = eta_b;
      gemm_k<MKVAE, 32, 32, 2, 2, 512, 1040><<<dim3(16, 33), 256, 0, stream>>>(p);
    }
    // G4: state update + mem_ctx_{t+1} (slot 64 = last_item query for final read)
    state_k<true><<<cB * cH / 4, 256, 0, stream>>>(
        (t == 0) ? init_state : state, state, k_raw, v_buf, alpha_b, eta_b,
        q_all + (size_t)(t + 1) * cB * cD, mem_ctx);
  }

  {  // F1: x = user + mem_ctx @ Wo + bo
    GemmArgs p{}; p.A = mem_ctx; p.W = Wo; p.bias = bo; p.extra = user_stat; p.O = x_buf;
    gemm_k<MWO, 32, 32, 2, 2, 512, 0><<<dim3(16, 16), 256, 0, stream>>>(p);
  }
  row_stats_k<<<cB / 4, 256, 0, stream>>>(x_buf, xm, xr);
  {  // F2: u = relu(LN(x) @ W1 + b1)
    GemmArgs p{}; p.A = x_buf; p.sm = xm; p.sr = xr; p.g = n2g; p.b = n2b;
    p.W = W1; p.bias = b1; p.O = u_buf;
    gemm_k<MFF1, 64, 64, 4, 4, 512, 0><<<dim3(8, 32), 256, 0, stream>>>(p);
  }
  {  // F3: out = x + u @ W2 + b2
    GemmArgs p{}; p.A = u_buf; p.W = W2; p.bias = b2; p.extra = x_buf;
    p.O = (float*)d_out;
    gemm_k<MFF2, 32, 32, 2, 2, 2048, 0><<<dim3(16, 16), 256, 0, stream>>>(p);
  }
}

// Round 2
// 9112.378 us; speedup vs baseline: 1.2961x; 1.2961x over previous
//
#include <hip/hip_runtime.h>
#include <cmath>

constexpr int cB = 512, cT = 64, cD = 512, cH = 8, cDH = 64, cFF = 2048;
constexpr float cSCALE = 0.125f;  // DH^-0.5

typedef short bfrag __attribute__((ext_vector_type(8)));   // 8 bf16 = 4 VGPRs
typedef float f32x4 __attribute__((ext_vector_type(4)));

__device__ __forceinline__ short f2bf(float x) {
  union { float f; unsigned u; } v{x};
  unsigned r = v.u + 0x7fff + ((v.u >> 16) & 1);
  return (short)(r >> 16);
}
__device__ __forceinline__ float bf2f(short s) {
  union { unsigned u; float f; } v;
  v.u = ((unsigned)(unsigned short)s) << 16;
  return v.f;
}
__device__ __forceinline__ float sigm(float z) { return 1.f / (1.f + __expf(-z)); }

enum GemmMode { MQ = 0, MMETA1, MMETA2, MKVAE, MWO, MFF1, MFF2 };

struct GemmArgs {
  const float *A, *A2, *sm, *sr, *g, *b;
  const short *WT;
  const float *bias, *bias2, *extra;
  float *O, *O2, *O3, *O4;
  short *Os;
  int t;
};

// ---------------- A-loaders (row r, col k) -> fp32 (converted to bf16 at staging) ----
template<int MODE>
__device__ __forceinline__ float loadA(const GemmArgs& p, int r, int k) {
  if constexpr (MODE == MQ) {
    // rows: r = t*B + b, t<64 -> item_seq[b][t], t==64 -> last_item[b]
    int t = r >> 9, bb = r & 511;
    float v = (t < cT) ? p.A[((size_t)bb * cT + t) * cD + k]
                       : p.A2[(size_t)bb * cD + k];
    return (v - p.sm[r]) * p.sr[r] * p.g[k] + p.b[k];
  } else if constexpr (MODE == MMETA1) {
    return (k < cD) ? p.A[(size_t)r * cD + k] : p.A2[(size_t)r * cD + (k - cD)];
  } else if constexpr (MODE == MMETA2) {
    float v = (p.A[(size_t)r * cD + k] - p.sm[r]) * p.sr[r] * p.g[k] + p.b[k];
    return fmaxf(v, 0.f);  // relu(LN(r_buf))
  } else if constexpr (MODE == MKVAE) {
    // mod = i_norm*(1+tanh(gamma)) + beta, fused
    float inm = (p.A[((size_t)r * cT + p.t) * cD + k] - p.sm[p.t * cB + r]) *
                    p.sr[p.t * cB + r] * p.g[k] + p.b[k];
    float gam = p.A2[(size_t)r * 1040 + k];
    float bet = p.A2[(size_t)r * 1040 + 512 + k];
    return inm * (1.f + tanhf(gam)) + bet;
  } else if constexpr (MODE == MFF1) {
    return (p.A[(size_t)r * cD + k] - p.sm[r]) * p.sr[r] * p.g[k] + p.b[k];
  } else if constexpr (MODE == MFF2) {
    return p.A[(size_t)r * cFF + k];
  } else {  // MWO
    return p.A[(size_t)r * cD + k];
  }
}

// ---------------- epilogues ----------------
template<int MODE>
__device__ __forceinline__ void epi(const GemmArgs& p, int r, int cn, float acc) {
  if constexpr (MODE == MQ) {
    p.Os[(size_t)r * cD + cn] = f2bf(acc);  // raw q, bf16 (l2n at consumer)
  } else if constexpr (MODE == MMETA1) {
    p.O[(size_t)r * cD + cn] = acc + p.bias[cn];
  } else if constexpr (MODE == MMETA2) {
    p.O[(size_t)r * 1040 + cn] = acc + p.bias[cn];
  } else if constexpr (MODE == MKVAE) {
    if (cn < 512) {
      p.O[(size_t)r * cD + cn] = acc;                       // k raw
    } else if (cn < 1024) {
      p.O2[(size_t)r * cD + (cn - 512)] = acc;              // v
    } else if (cn < 1032) {
      int h = cn - 1024;
      p.O3[r * cH + h] = sigm(acc + p.bias[h] + p.extra[(size_t)r * 1040 + 1024 + h]);
    } else {
      int h = cn - 1032;
      p.O4[r * cH + h] = cSCALE * sigm(acc + p.bias2[h] + p.extra[(size_t)r * 1040 + 1032 + h]);
    }
  } else if constexpr (MODE == MWO) {
    p.O[(size_t)r * cD + cn] = p.extra[(size_t)r * cD + cn] + acc + p.bias[cn];
  } else if constexpr (MODE == MFF1) {
    p.O[(size_t)r * cFF + cn] = fmaxf(acc + p.bias[cn], 0.f);
  } else {  // MFF2: out = x + ffn
    p.O[(size_t)r * cD + cn] = p.extra[(size_t)r * cD + cn] + acc + p.bias[cn];
  }
}

// ---------------- bf16 MFMA GEMM ----------------
// 256 threads = 4 waves (2x2), block tile 64x64, wave tile 32x32 (2x2 frags of
// 16x16), K-panel 32 (one mfma_f32_16x16x32_bf16 K-chunk).
// A staged fp32->bf16 with fused transform; W pre-converted bf16 W^T[n][k].
template<int MODE, int LDW, int NV>
__global__ __launch_bounds__(256) void mgemm(GemmArgs p, int K) {
  __shared__ short As[64][32];  // [m][k]
  __shared__ short Bs[64][32];  // [n][k]
  const int tid = threadIdx.x;
  const int lane = tid & 63, wid = tid >> 6;
  const int wm = wid & 1, wn = wid >> 1;
  const int l15 = lane & 15, qd = lane >> 4;
  const int row0 = blockIdx.x * 64;
  const int n0 = blockIdx.y * 64;

  f32x4 acc[2][2] = {};

  const int sm = tid >> 2;          // staging row 0..63
  const int sk = (tid & 3) * 8;     // staging k-chunk

  for (int k0 = 0; k0 < K; k0 += 32) {
    {  // stage A (with transform + bf16 convert)
      short tmp[8];
#pragma unroll
      for (int j = 0; j < 8; ++j)
        tmp[j] = f2bf(loadA<MODE>(p, row0 + sm, k0 + sk + j));
      *((bfrag*)&As[sm][0] + (sk >> 3)) = *(bfrag*)tmp;
    }
    {  // stage B from pre-converted W^T (16B vector load)
      bfrag w = {};
      if (NV == 0 || n0 + sm < NV)
        w = *(const bfrag*)(p.WT + (size_t)(n0 + sm) * LDW + k0 + sk);
      *((bfrag*)&Bs[sm][0] + (sk >> 3)) = w;
    }
    __syncthreads();
    bfrag a0 = *((bfrag*)&As[wm * 32 + l15][0] + qd);
    bfrag a1 = *((bfrag*)&As[wm * 32 + 16 + l15][0] + qd);
    bfrag b0 = *((bfrag*)&Bs[wn * 32 + l15][0] + qd);
    bfrag b1 = *((bfrag*)&Bs[wn * 32 + 16 + l15][0] + qd);
    acc[0][0] = __builtin_amdgcn_mfma_f32_16x16x32_bf16(a0, b0, acc[0][0], 0, 0, 0);
    acc[0][1] = __builtin_amdgcn_mfma_f32_16x16x32_bf16(a0, b1, acc[0][1], 0, 0, 0);
    acc[1][0] = __builtin_amdgcn_mfma_f32_16x16x32_bf16(a1, b0, acc[1][0], 0, 0, 0);
    acc[1][1] = __builtin_amdgcn_mfma_f32_16x16x32_bf16(a1, b1, acc[1][1], 0, 0, 0);
    __syncthreads();
  }

#pragma unroll
  for (int fm = 0; fm < 2; ++fm)
#pragma unroll
    for (int fn = 0; fn < 2; ++fn)
#pragma unroll
      for (int rg = 0; rg < 4; ++rg) {
        int r = row0 + wm * 32 + fm * 16 + qd * 4 + rg;
        int cn = n0 + wn * 32 + fn * 16 + l15;
        if (NV == 0 || cn < NV) epi<MODE>(p, r, cn, acc[fm][fn][rg]);
      }
}

// ---------------- weight transpose + bf16 convert: W[K][N] -> WT[N][K] ----------
__global__ __launch_bounds__(256) void tconv(const float* __restrict__ W,
                                             short* __restrict__ WT, int K, int N) {
  __shared__ float tile[32][33];
  int k0 = blockIdx.x * 32, n0 = blockIdx.y * 32;
  int tx = threadIdx.x & 31, ty = threadIdx.x >> 5;  // ty 0..7
#pragma unroll
  for (int j = 0; j < 32; j += 8) {
    int k = k0 + ty + j, n = n0 + tx;
    tile[ty + j][tx] = (k < K && n < N) ? W[(size_t)k * N + n] : 0.f;
  }
  __syncthreads();
#pragma unroll
  for (int j = 0; j < 32; j += 8) {
    int n = n0 + ty + j, k = k0 + tx;
    if (n < N && k < K) WT[(size_t)n * K + k] = f2bf(tile[tx][ty + j]);
  }
}

// ---------------- LN stats for item/last rows + us_norm ----------------
__global__ __launch_bounds__(256) void ln_stats_k(
    const float* __restrict__ item_seq, const float* __restrict__ last_item,
    const float* __restrict__ user, const float* __restrict__ n1g,
    const float* __restrict__ n1b, float* __restrict__ lnm,
    float* __restrict__ lnr, float* __restrict__ us_norm) {
  const int lane = threadIdx.x & 63;
  const int w = blockIdx.x * 4 + (threadIdx.x >> 6);
  const float* src;
  int cls, bi = 0;
  if (w < cT * cB) {
    int t = w >> 9, bb = w & 511;
    src = item_seq + ((size_t)bb * cT + t) * cD;
    cls = 0;
  } else if (w < cT * cB + cB) {
    bi = w - cT * cB;
    src = last_item + (size_t)bi * cD;
    cls = 1;
  } else {
    bi = w - cT * cB - cB;
    src = user + (size_t)bi * cD;
    cls = 2;
  }
  float x[8], s = 0.f, ss = 0.f;
#pragma unroll
  for (int i = 0; i < 8; ++i) {
    float v = src[lane + i * 64];
    x[i] = v; s += v; ss += v * v;
  }
#pragma unroll
  for (int o = 32; o >= 1; o >>= 1) { s += __shfl_xor(s, o); ss += __shfl_xor(ss, o); }
  float m = s * (1.f / cD);
  float rstd = rsqrtf(ss * (1.f / cD) - m * m + 1e-5f);
  if (cls == 0) {
    if (lane == 0) { lnm[w] = m; lnr[w] = rstd; }
  } else if (cls == 1) {
    if (lane == 0) { lnm[cT * cB + bi] = m; lnr[cT * cB + bi] = rstd; }
  } else {
#pragma unroll
    for (int i = 0; i < 8; ++i) {
      int d = lane + i * 64;
      us_norm[(size_t)bi * cD + d] = (x[i] - m) * rstd * n1g[d] + n1b[d];
    }
  }
}

// ---------------- per-row stats (512 rows x 512 cols) ----------------
__global__ __launch_bounds__(256) void row_stats_k(const float* __restrict__ X,
                                                   float* __restrict__ M,
                                                   float* __restrict__ R) {
  const int lane = threadIdx.x & 63;
  const int w = blockIdx.x * 4 + (threadIdx.x >> 6);
  float s = 0.f, ss = 0.f;
#pragma unroll
  for (int i = 0; i < 8; ++i) {
    float v = X[(size_t)w * cD + lane + i * 64];
    s += v; ss += v * v;
  }
#pragma unroll
  for (int o = 32; o >= 1; o >>= 1) { s += __shfl_xor(s, o); ss += __shfl_xor(ss, o); }
  if (lane == 0) {
    float m = s * (1.f / cD);
    M[w] = m;
    R[w] = rsqrtf(ss * (1.f / cD) - m * m + 1e-5f);
  }
}

// ---------------- fused state update + memory read ----------------
// one wave per (b,h); lane i holds state row i (64 floats in VGPRs)
template<bool UPD>
__global__ __launch_bounds__(256) void state_k(
    const float* __restrict__ Sin, float* __restrict__ Sout,
    const float* __restrict__ k_raw, const float* __restrict__ v_buf,
    const float* __restrict__ alpha, const float* __restrict__ eta,
    const short* __restrict__ q_row, float* __restrict__ mem_ctx) {
  const int lane = threadIdx.x & 63;
  const int wi = threadIdx.x >> 6;
  const int w = blockIdx.x * 4 + wi;
  const int b = w >> 3, h = w & 7;
  __shared__ float sk[4][64];
  __shared__ float sq[4][64];

  float q = bf2f(q_row[(size_t)b * cD + h * cDH + lane]);
  float qs = q * q;
#pragma unroll
  for (int o = 32; o >= 1; o >>= 1) qs += __shfl_xor(qs, o);
  sq[wi][lane] = q / fmaxf(sqrtf(qs), 1e-12f);

  if constexpr (UPD) {
    float kv = k_raw[(size_t)b * cD + h * cDH + lane];
    float ks = kv * kv;
#pragma unroll
    for (int o = 32; o >= 1; o >>= 1) ks += __shfl_xor(ks, o);
    sk[wi][lane] = kv / fmaxf(sqrtf(ks), 1e-12f);
  }
  // only intra-wave LDS use: no __syncthreads needed

  float S[64];
  const float* sp = Sin + ((size_t)w * cDH + lane) * cDH;
#pragma unroll
  for (int j = 0; j < 64; j += 4) {
    float4 t4 = *(const float4*)(sp + j);
    S[j] = t4.x; S[j + 1] = t4.y; S[j + 2] = t4.z; S[j + 3] = t4.w;
  }

  float mem = 0.f;
  if constexpr (UPD) {
    float vv = v_buf[(size_t)b * cD + h * cDH + lane];
    float a = alpha[b * cH + h];
    float e = eta[b * cH + h];
    float pred = 0.f;
#pragma unroll
    for (int j = 0; j < 64; ++j) pred += S[j] * sk[wi][j];
    float f = e * (vv - pred);
    float oma = 1.f - a;
#pragma unroll
    for (int j = 0; j < 64; ++j) {
      S[j] = oma * S[j] + f * sk[wi][j];
      mem += S[j] * sq[wi][j];
    }
    float* op = Sout + ((size_t)w * cDH + lane) * cDH;
#pragma unroll
    for (int j = 0; j < 64; j += 4) {
      float4 t4 = make_float4(S[j], S[j + 1], S[j + 2], S[j + 3]);
      *(float4*)(op + j) = t4;
    }
  } else {
#pragma unroll
    for (int j = 0; j < 64; ++j) mem += S[j] * sq[wi][j];
  }
  mem_ctx[(size_t)b * cD + h * cDH + lane] = mem;
}

// ---------------- host launch ----------------
extern "C" void kernel_launch(void* const* d_in, const int* in_sizes, int n_in,
                              void* d_out, int out_size, void* d_ws, size_t ws_size,
                              hipStream_t stream) {
  (void)in_sizes; (void)n_in; (void)out_size;
  const float* item_seq   = (const float*)d_in[0];
  const float* user_stat  = (const float*)d_in[1];
  const float* last_item  = (const float*)d_in[2];
  const float* init_state = (const float*)d_in[3];
  const float* Wq  = (const float*)d_in[4];
  const float* Wk  = (const float*)d_in[5];
  const float* Wv  = (const float*)d_in[6];
  const float* Wa  = (const float*)d_in[7];
  const float* ba  = (const float*)d_in[8];
  const float* We  = (const float*)d_in[9];
  const float* be  = (const float*)d_in[10];
  const float* mcW1 = (const float*)d_in[11];
  const float* mcb1 = (const float*)d_in[12];
  const float* mcg  = (const float*)d_in[13];
  const float* mcbt = (const float*)d_in[14];
  const float* mcW2 = (const float*)d_in[15];
  const float* mcb2 = (const float*)d_in[16];
  const float* Wo  = (const float*)d_in[17];
  const float* bo  = (const float*)d_in[18];
  const float* W1  = (const float*)d_in[19];
  const float* b1  = (const float*)d_in[20];
  const float* W2  = (const float*)d_in[21];
  const float* b2  = (const float*)d_in[22];
  const float* n1g = (const float*)d_in[23];
  const float* n1b = (const float*)d_in[24];
  const float* n2g = (const float*)d_in[25];
  const float* n2b = (const float*)d_in[26];

  float* ws = (float*)d_ws;
  size_t off = 0;
  auto alloc = [&](size_t n) { float* p = ws + off; off += n; return p; };
  auto salloc = [&](size_t n) { return (short*)alloc((n + 1) / 2); };

  short* q_all   = salloc((size_t)(cT + 1) * cB * cD);  // bf16 raw q, 65 slots
  float* state   = alloc((size_t)cB * cH * cDH * cDH);
  float* lnm     = alloc((size_t)(cT + 1) * cB);
  float* lnr     = alloc((size_t)(cT + 1) * cB);
  float* us_norm = alloc((size_t)cB * cD);
  float* mem_ctx = alloc((size_t)cB * cD);
  float* r_buf   = alloc((size_t)cB * cD);
  float* rm      = alloc(cB);
  float* rr      = alloc(cB);
  float* mo_buf  = alloc((size_t)cB * 1040);
  float* k_raw   = alloc((size_t)cB * cD);
  float* v_buf   = alloc((size_t)cB * cD);
  float* alpha_b = alloc((size_t)cB * cH);
  float* eta_b   = alloc((size_t)cB * cH);
  float* x_buf   = alloc((size_t)cB * cD);
  float* xm      = alloc(cB);
  float* xr      = alloc(cB);
  float* u_buf   = alloc((size_t)cB * cFF);
  // bf16 transposed weights WT[n][k]
  short* wt_q    = salloc((size_t)512 * 512);
  short* wt_m1   = salloc((size_t)512 * 1024);
  short* wt_m2   = salloc((size_t)1040 * 512);
  short* wt_kvae = salloc((size_t)1040 * 512);
  short* wt_o    = salloc((size_t)512 * 512);
  short* wt_1    = salloc((size_t)2048 * 512);
  short* wt_2    = salloc((size_t)512 * 2048);
  if (ws_size < off * sizeof(float)) return;

  // --- one-time prep ---
  tconv<<<dim3(16, 16), 256, 0, stream>>>(Wq, wt_q, 512, 512);
  tconv<<<dim3(32, 16), 256, 0, stream>>>(mcW1, wt_m1, 1024, 512);
  tconv<<<dim3(16, 33), 256, 0, stream>>>(mcW2, wt_m2, 512, 1040);
  tconv<<<dim3(16, 16), 256, 0, stream>>>(Wk, wt_kvae, 512, 512);
  tconv<<<dim3(16, 16), 256, 0, stream>>>(Wv, wt_kvae + (size_t)512 * 512, 512, 512);
  tconv<<<dim3(16, 1), 256, 0, stream>>>(Wa, wt_kvae + (size_t)1024 * 512, 512, 8);
  tconv<<<dim3(16, 1), 256, 0, stream>>>(We, wt_kvae + (size_t)1032 * 512, 512, 8);
  tconv<<<dim3(16, 16), 256, 0, stream>>>(Wo, wt_o, 512, 512);
  tconv<<<dim3(16, 64), 256, 0, stream>>>(W1, wt_1, 512, 2048);
  tconv<<<dim3(64, 16), 256, 0, stream>>>(W2, wt_2, 2048, 512);

  ln_stats_k<<<(cT * cB + 2 * cB) / 4, 256, 0, stream>>>(
      item_seq, last_item, user_stat, n1g, n1b, lnm, lnr, us_norm);

  {  // q_all = LN(item/last) @ Wq for all 65 slots (bf16 out)
    GemmArgs p{}; p.A = item_seq; p.A2 = last_item; p.sm = lnm; p.sr = lnr;
    p.g = n1g; p.b = n1b; p.WT = wt_q; p.Os = q_all;
    mgemm<MQ, 512, 0><<<dim3(520, 8), 256, 0, stream>>>(p, 512);
  }

  // mem_ctx_0 = init_state . q_0
  state_k<false><<<cB * cH / 4, 256, 0, stream>>>(
      init_state, nullptr, nullptr, nullptr, nullptr, nullptr, q_all, mem_ctx);

  for (int t = 0; t < cT; ++t) {
    {  // r = [us_norm|mem_ctx] @ mcW1 + mcb1
      GemmArgs p{}; p.A = us_norm; p.A2 = mem_ctx; p.WT = wt_m1; p.bias = mcb1; p.O = r_buf;
      mgemm<MMETA1, 1024, 0><<<dim3(8, 8), 256, 0, stream>>>(p, 1024);
    }
    row_stats_k<<<cB / 4, 256, 0, stream>>>(r_buf, rm, rr);
    {  // mo = relu(LN(r)) @ mcW2 + mcb2
      GemmArgs p{}; p.A = r_buf; p.sm = rm; p.sr = rr; p.g = mcg; p.b = mcbt;
      p.WT = wt_m2; p.bias = mcb2; p.O = mo_buf;
      mgemm<MMETA2, 512, 1040><<<dim3(8, 17), 256, 0, stream>>>(p, 512);
    }
    {  // [k|v|alpha|eta] = mod(fused) @ [Wk|Wv|Wa|We]
      GemmArgs p{}; p.A = item_seq; p.A2 = mo_buf; p.sm = lnm; p.sr = lnr;
      p.g = n1g; p.b = n1b; p.t = t; p.WT = wt_kvae;
      p.bias = ba; p.bias2 = be; p.extra = mo_buf;
      p.O = k_raw; p.O2 = v_buf; p.O3 = alpha_b; p.O4 = eta_b;
      mgemm<MKVAE, 512, 1040><<<dim3(8, 17), 256, 0, stream>>>(p, 512);
    }
    // state update + mem_ctx_{t+1} (slot 64 = last_item query)
    state_k<true><<<cB * cH / 4, 256, 0, stream>>>(
        (t == 0) ? init_state : state, state, k_raw, v_buf, alpha_b, eta_b,
        q_all + (size_t)(t + 1) * cB * cD, mem_ctx);
  }

  {  // x = user + mem_ctx @ Wo + bo
    GemmArgs p{}; p.A = mem_ctx; p.WT = wt_o; p.bias = bo; p.extra = user_stat; p.O = x_buf;
    mgemm<MWO, 512, 0><<<dim3(8, 8), 256, 0, stream>>>(p, 512);
  }
  row_stats_k<<<cB / 4, 256, 0, stream>>>(x_buf, xm, xr);
  {  // u = relu(LN(x) @ W1 + b1)
    GemmArgs p{}; p.A = x_buf; p.sm = xm; p.sr = xr; p.g = n2g; p.b = n2b;
    p.WT = wt_1; p.bias = b1; p.O = u_buf;
    mgemm<MFF1, 512, 0><<<dim3(8, 32), 256, 0, stream>>>(p, 512);
  }
  {  // out = x + u @ W2 + b2
    GemmArgs p{}; p.A = u_buf; p.WT = wt_2; p.bias = b2; p.extra = x_buf;
    p.O = (float*)d_out;
    mgemm<MFF2, 2048, 0><<<dim3(8, 8), 256, 0, stream>>>(p, 2048);
  }
}